// Round 12
// baseline (68.824 us; speedup 1.0000x reference)
//
#include <hip/hip_runtime.h>
#include <hip/hip_bf16.h>

typedef __attribute__((ext_vector_type(8))) short s16x8;
typedef __attribute__((ext_vector_type(4))) float fx4;
typedef __attribute__((ext_vector_type(4))) unsigned int u32x4;
typedef unsigned short u16;
typedef unsigned int   u32;
typedef unsigned long long u64;

#define DI __device__ __forceinline__

// B=2, W=512, E=2, P=8, H=1024, NH=16, D=64, T=514
// External I/O: float32. Internal workspace: bf16 (MFMA).

DI float bf2f(u16 x){ u32 u = ((u32)x)<<16; float f; __builtin_memcpy(&f,&u,4); return f; }
DI u16 f2bf(float f){ u32 u; __builtin_memcpy(&u,&f,4); u = (u + 0x7fffu + ((u>>16)&1u))>>16; return (u16)u; }

DI fx4 mfma_16x16x32_bf16(s16x8 a, s16x8 b, fx4 c){
  return __builtin_amdgcn_mfma_f32_16x16x32_bf16(a,b,c,0,0,0);
}

// ---------------- K_prep: fused weight transpose (f32 k,n -> bf16 n,k) + activations cvt ----
__global__ __launch_bounds__(256) void k_prep(
    const float* __restrict__ s0, const float* __restrict__ s1, const float* __restrict__ s2,
    const float* __restrict__ s3, const float* __restrict__ s4, const float* __restrict__ s5,
    u16* __restrict__ dstbase,
    const float* __restrict__ words, u16* __restrict__ Xbf,
    const float* __restrict__ ents,  u16* __restrict__ Ebf)
{
  __shared__ __align__(16) u16 tile[64][72];
  int bx = blockIdx.x, tid = threadIdx.x;
  if(bx < 1536){
    int z = bx>>8, t = bx&255;
    const float* src = (z==0)?s0:(z==1)?s1:(z==2)?s2:(z==3)?s3:(z==4)?s4:s5;
    u16* dst = dstbase + (u64)z*1048576u;
    int kt = (t&15)*64, nt = (t>>4)*64;
    #pragma unroll
    for(int it=0; it<2; ++it){
      int c = it*256 + tid;
      int r = c>>3, col = (c&7)*8;
      const float* sp = src + (u64)(kt+r)*1024u + nt + col;
      fx4 a = *(const fx4*)sp;
      fx4 b = *(const fx4*)(sp+4);
      u16 o[8];
      o[0]=f2bf(a[0]); o[1]=f2bf(a[1]); o[2]=f2bf(a[2]); o[3]=f2bf(a[3]);
      o[4]=f2bf(b[0]); o[5]=f2bf(b[1]); o[6]=f2bf(b[2]); o[7]=f2bf(b[3]);
      __builtin_memcpy(&tile[r][col], o, 16);
    }
    __syncthreads();
    #pragma unroll
    for(int it=0; it<2; ++it){
      int c = it*256 + tid;
      int nr = c>>3, kc = (c&7)*8;
      u16 tmp[8];
      #pragma unroll
      for(int j=0;j<8;++j) tmp[j] = tile[kc+j][nr];
      u32x4 v; __builtin_memcpy(&v, tmp, 16);
      *(u32x4*)(dst + (u64)(nt+nr)*1024u + kt + kc) = v;
    }
  } else {
    const float* src; u16* dst; int i;
    if(bx < 2048){ src = words; dst = Xbf; i = ((bx-1536)*256 + tid)*8; }
    else         { src = ents;  dst = Ebf; i = ((bx-2048)*256 + tid)*8; }
    fx4 a = *(const fx4*)(src+i);
    fx4 b = *(const fx4*)(src+i+4);
    u16 o[8];
    o[0]=f2bf(a[0]); o[1]=f2bf(a[1]); o[2]=f2bf(a[2]); o[3]=f2bf(a[3]);
    o[4]=f2bf(b[0]); o[5]=f2bf(b[1]); o[6]=f2bf(b[2]); o[7]=f2bf(b[3]);
    u32x4 v; __builtin_memcpy(&v,o,16);
    *(u32x4*)(dst+i)=v;
  }
}

// ---------------- K_proj: all 8 projections in one launch (round-5 structure) --------------
__global__ __launch_bounds__(256) void k_proj(
    const u16* __restrict__ Xbf, const u16* __restrict__ Ebf,
    const u16* __restrict__ wtq, const u16* __restrict__ wtw2e,
    const u16* __restrict__ wtk, const u16* __restrict__ wtv,
    const u16* __restrict__ wte2w, const u16* __restrict__ wte2e,
    const float* __restrict__ qb, const float* __restrict__ w2eb,
    const float* __restrict__ kb, const float* __restrict__ vb,
    const float* __restrict__ e2wb, const float* __restrict__ e2eb,
    u16* __restrict__ Qw, u16* __restrict__ Q2e, u16* __restrict__ Kwp, u16* __restrict__ VwTp,
    u16* __restrict__ Qe2w, u16* __restrict__ Qe2e, u16* __restrict__ Kep, u16* __restrict__ VeTp)
{
  __shared__ __align__(16) u16 XL[128*64];
  __shared__ __align__(16) u16 WL[128*64];
  int tid = threadIdx.x;
  int z = blockIdx.z;
  int wv = tid>>6, lane = tid&63, l15 = lane&15, g = lane>>4;

  if(blockIdx.y < 8){
    const u16* WT  = (z==0)?wtq:(z==1)?wtw2e:(z==2)?wtk:wtv;
    const float* bias = (z==0)?qb :(z==1)?w2eb :(z==2)?kb :vb;
    u16* out       = (z==0)?Qw :(z==1)?Q2e :(z==2)?Kwp :VwTp;
    int nt = blockIdx.x*64;
    int mt = blockIdx.y*128;
    int wr = (wv>>1)*64, wc = (wv&1)*32;
    fx4 acc[4][2] = {};
    u32x4 rx[4], rw[2];
    #pragma unroll
    for(int it=0; it<4; ++it){
      int c = it*256 + tid;
      int r = c>>3, cb = (c&7)*16, scb = cb ^ ((r&7)<<4);
      rx[it] = *(const u32x4*)((const char*)Xbf + ((u64)(mt+r)*1024u)*2u + scb);
    }
    #pragma unroll
    for(int it=0; it<2; ++it){
      int c = it*256 + tid;
      int r = c>>3, cb = (c&7)*16, scb = cb ^ ((r&7)<<4);
      rw[it] = *(const u32x4*)((const char*)WT + ((u64)(nt+r)*1024u)*2u + scb);
    }
    #pragma unroll
    for(int it=0; it<4; ++it) *(u32x4*)((char*)XL + (it*256+tid)*16) = rx[it];
    #pragma unroll
    for(int it=0; it<2; ++it) *(u32x4*)((char*)WL + (it*256+tid)*16) = rw[it];
    __syncthreads();
    for(int t=0; t<16; ++t){
      int kn = (t+1)*64;
      if(t < 15){
        #pragma unroll
        for(int it=0; it<4; ++it){
          int c = it*256 + tid;
          int r = c>>3, cb = (c&7)*16, scb = cb ^ ((r&7)<<4);
          rx[it] = *(const u32x4*)((const char*)Xbf + ((u64)(mt+r)*1024u + kn)*2u + scb);
        }
        #pragma unroll
        for(int it=0; it<2; ++it){
          int c = it*256 + tid;
          int r = c>>3, cb = (c&7)*16, scb = cb ^ ((r&7)<<4);
          rw[it] = *(const u32x4*)((const char*)WT + ((u64)(nt+r)*1024u + kn)*2u + scb);
        }
      }
      #pragma unroll
      for(int ks=0; ks<2; ++ks){
        s16x8 af[4], bfv[2];
        #pragma unroll
        for(int i=0;i<4;++i){
          int ra = wr + i*16 + l15;
          af[i]  = *(const s16x8*)((const char*)XL + ra*128 + ((ks*64 + g*16) ^ ((ra&7)<<4)));
        }
        #pragma unroll
        for(int j=0;j<2;++j){
          int rb = wc + j*16 + l15;
          bfv[j] = *(const s16x8*)((const char*)WL + rb*128 + ((ks*64 + g*16) ^ ((rb&7)<<4)));
        }
        #pragma unroll
        for(int i=0;i<4;++i)
          #pragma unroll
          for(int j=0;j<2;++j)
            acc[i][j] = mfma_16x16x32_bf16(af[i], bfv[j], acc[i][j]);
      }
      __syncthreads();
      if(t < 15){
        #pragma unroll
        for(int it=0; it<4; ++it) *(u32x4*)((char*)XL + (it*256+tid)*16) = rx[it];
        #pragma unroll
        for(int it=0; it<2; ++it) *(u32x4*)((char*)WL + (it*256+tid)*16) = rw[it];
        __syncthreads();
      }
    }
    bool vmode = (z==3);
    #pragma unroll
    for(int j=0;j<2;++j){
      int n = nt + wc + j*16 + l15;
      float bv = bias[n];
      int h = n>>6, d = n&63;
      #pragma unroll
      for(int i=0;i<4;++i){
        #pragma unroll
        for(int q=0;q<4;++q){
          int m = mt + wr + i*16 + g*4 + q;
          int bb = m>>9, wrow = m&511;
          float v = acc[i][j][q] + bv;
          u64 o = vmode ? (((u64)(bb*16+h)*64u + d)*512u + wrow)
                        : (((u64)(bb*16+h)*512u + wrow)*64u + d);
          out[o] = f2bf(v);
        }
      }
    }
  } else {
    if(blockIdx.x >= 8) return;
    const u16* WT  = (z==0)?wte2w:(z==1)?wte2e:(z==2)?wtk:wtv;
    const float* bias = (z==0)?e2wb :(z==1)?e2eb :(z==2)?kb :vb;
    u16* out       = (z==0)?Qe2w :(z==1)?Qe2e :(z==2)?Kep :VeTp;
    int nt = blockIdx.x*128;
    int wc = wv*32;
    fx4 acc[2][2] = {};
    for(int kk=0; kk<1024; kk+=64){
      {
        int r = tid>>3, cb = (tid&7)*16, scb = cb ^ ((r&7)<<4);
        *(u32x4*)((char*)XL + r*128 + cb) =
          *(const u32x4*)((const char*)Ebf + ((u64)r*1024u + kk)*2u + scb);
      }
      #pragma unroll
      for(int it=0; it<4; ++it){
        int c = it*256 + tid;
        int r = c>>3, cb = (c&7)*16, scb = cb ^ ((r&7)<<4);
        *(u32x4*)((char*)WL + r*128 + cb) =
          *(const u32x4*)((const char*)WT + ((u64)(nt+r)*1024u + kk)*2u + scb);
      }
      __syncthreads();
      #pragma unroll
      for(int ks=0; ks<2; ++ks){
        s16x8 af[2], bfv[2];
        #pragma unroll
        for(int i=0;i<2;++i){
          int ra = i*16 + l15;
          af[i]  = *(const s16x8*)((const char*)XL + ra*128 + ((ks*64 + g*16) ^ ((ra&7)<<4)));
          int rb = wc + i*16 + l15;
          bfv[i] = *(const s16x8*)((const char*)WL + rb*128 + ((ks*64 + g*16) ^ ((rb&7)<<4)));
        }
        #pragma unroll
        for(int i=0;i<2;++i)
          #pragma unroll
          for(int j=0;j<2;++j)
            acc[i][j] = mfma_16x16x32_bf16(af[i], bfv[j], acc[i][j]);
      }
      __syncthreads();
    }
    bool vmode = (z==3);
    #pragma unroll
    for(int j=0;j<2;++j){
      int n = nt + wc + j*16 + l15;
      float bv = bias[n];
      int h = n>>6, d = n&63;
      #pragma unroll
      for(int i=0;i<2;++i){
        #pragma unroll
        for(int q=0;q<4;++q){
          int m = i*16 + g*4 + q;     // 0..31 = ((b*8+p)*2+e)
          int bb = m>>4, p = (m>>1)&7, e = m&1;
          float v = acc[i][j][q] + bv;
          u64 base = ((u64)(bb*8+p)*16u + h);
          u64 o = vmode ? ((base*64u + d)*2u + e)
                        : ((base*2u + e)*64u + d);
          out[o] = f2bf(v);
        }
      }
    }
  }
}

// ---------------- K_attn: word-query flash attention + entity-query rows ----------------
// grid (24, 16, 2): x<16 -> word path (qc=x, 32 q-rows/block, 8 rows/wave on a 16-row MFMA
// tile, lanes 8-15 compute unclamped-garbage that is never stored); x>=16 -> entity (p=x-16).
// LDS diet: 50 KB -> 3 blocks/CU. se in VGPRs (+shfl), Ve direct from L2, entity arrays
// union'd into KL.
__global__ __launch_bounds__(256) void k_attn(
    const u16* __restrict__ Qw,  const u16* __restrict__ Q2e,
    const u16* __restrict__ Kw,  const u16* __restrict__ VwT,
    const u16* __restrict__ Ke,  const u16* __restrict__ VeT,
    const u16* __restrict__ Qe2w, const u16* __restrict__ Qe2e,
    const float* __restrict__ msk, float* __restrict__ outw, float* __restrict__ oute)
{
  const float scale = 0.125f;
  __shared__ __align__(16) u16 KL[128*64];        // 16 KB, rows 128B, swz ((r&7)<<4)
  __shared__ __align__(16) u16 VtL[64*128];       // 16 KB, rows 256B, swz ((r&15)<<4)
  __shared__ __align__(16) char UA[4][4096];      // union/wave: PT2 u16[16][128] | obuf f32[16][64], 256B rows
  __shared__ __align__(16) float mask_lds[516];   // 2.06 KB
  int tid = threadIdx.x;
  int h = blockIdx.y, b = blockIdx.z;
  int wv = tid>>6, lane = tid&63, l15 = lane&15, g = lane>>4;

  if(blockIdx.x < 16){
    // =================== word path (32 q-rows per block) ===================
    int qc = blockIdx.x;
    int q0 = qc*32 + wv*8;            // this wave's 8 query rows

    for(int i=tid;i<516;i+=256) mask_lds[i] = (i<514) ? msk[b*514+i] : 0.f;

    // Q and Q2 B-fragments; lane row clamped to the 8 valid rows (lanes 8-15 duplicate)
    int qrow = q0 + (l15&7);
    const u16* Qrow = Qw + ((u64)(b*16+h)*512u + qrow)*64u;
    s16x8 qf0 = *(const s16x8*)(Qrow + g*8);
    s16x8 qf1 = *(const s16x8*)(Qrow + 32 + g*8);
    const u16* Q2row = Q2e + ((u64)(b*16+h)*512u + qrow)*64u;
    s16x8 q2f0 = *(const s16x8*)(Q2row + g*8);
    s16x8 q2f1 = *(const s16x8*)(Q2row + 32 + g*8);
    // Ke A-fragment: lane row = pe = l15 (p=l15>>1, e=l15&1)
    const u16* kerow = Ke + ((u64)(b*8+(l15>>1))*16u + h)*128u + (u64)(l15&1)*64u;
    s16x8 keA0 = *(const s16x8*)(kerow + g*8);
    s16x8 keA1 = *(const s16x8*)(kerow + 32 + g*8);
    // entity scores kept in VGPRs: se[j] = D[pe=g*4+j][query=l15]
    fx4 se = {0.f,0.f,0.f,0.f};
    se = mfma_16x16x32_bf16(keA0, q2f0, se);
    se = mfma_16x16x32_bf16(keA1, q2f1, se);

    const char* Kpan = (const char*)(Kw  + (u64)(b*16+h)*512u*64u);   // 512 rows x 128B
    const char* Vpan = (const char*)(VwT + (u64)(b*16+h)*64u*512u);   // 64 rows x 1024B

    u32x4 rk[4], rv[4];
    auto LOADC = [&](int c){
      #pragma unroll
      for(int it=0;it<4;++it){
        int idx = it*256+tid;
        int r = idx>>3, cb = (idx&7)*16;
        rk[it] = *(const u32x4*)(Kpan + (u64)(c*128+r)*128u + cb);
        int vrr = idx>>4, vcb = (idx&15)*16;
        rv[it] = *(const u32x4*)(Vpan + (u64)vrr*1024u + (u64)c*256u + vcb);
      }
    };
    auto WRITEC = [&](){
      #pragma unroll
      for(int it=0;it<4;++it){
        int idx = it*256+tid;
        int r = idx>>3, cb = (idx&7)*16;
        *(u32x4*)((char*)KL + r*128 + (cb ^ ((r&7)<<4))) = rk[it];
        int vrr = idx>>4, vcb = (idx&15)*16;
        *(u32x4*)((char*)VtL + vrr*256 + (vcb ^ ((vrr&15)<<4))) = rv[it];
      }
    };

    LOADC(0); WRITEC();
    float m_run = -3.0e38f, l_run = 0.f;
    fx4 oacc[4] = {};
    __syncthreads();       // chunk 0 + mask ready

    char* prow = UA[wv] + l15*256;          // this lane's query row (PT2 / obuf)
    int swzP = (l15&15)<<4;
    for(int c=0;c<4;++c){
      if(c < 3) LOADC(c+1);         // next chunk in flight during compute
      // QK: S^T = K * Q^T, 128 keys
      float sv[8][4];
      #pragma unroll
      for(int s=0;s<8;++s){
        int row = s*16 + l15;
        const char* kr = (const char*)KL + row*128;
        int sz = (row&7)<<4;
        s16x8 ka0 = *(const s16x8*)(kr + ((g*16) ^ sz));
        s16x8 ka1 = *(const s16x8*)(kr + ((64 + g*16) ^ sz));
        fx4 st = {0.f,0.f,0.f,0.f};
        st = mfma_16x16x32_bf16(ka0, qf0, st);
        st = mfma_16x16x32_bf16(ka1, qf1, st);
        fx4 mk = *(const fx4*)&mask_lds[c*128 + s*16 + g*4];
        #pragma unroll
        for(int q=0;q<4;++q) sv[s][q] = st[q]*scale + mk[q];
      }
      float cm = -3.0e38f;
      #pragma unroll
      for(int s=0;s<8;++s)
        #pragma unroll
        for(int q=0;q<4;++q) cm = fmaxf(cm, sv[s][q]);
      cm = fmaxf(cm, __shfl_xor(cm, 16, 64));
      cm = fmaxf(cm, __shfl_xor(cm, 32, 64));
      float m_new = fmaxf(m_run, cm);
      float alpha = __expf(m_run - m_new);
      float rs = 0.f;
      #pragma unroll
      for(int s=0;s<8;++s){
        u16 pb4[4];
        #pragma unroll
        for(int q=0;q<4;++q){
          float e = __expf(sv[s][q] - m_new);
          rs += e;
          pb4[q] = f2bf(e);
        }
        u64 packed; __builtin_memcpy(&packed, pb4, 8);
        *(u64*)(prow + ((s*32 + g*8) ^ swzP)) = packed;
      }
      rs += __shfl_xor(rs, 16, 64);
      rs += __shfl_xor(rs, 32, 64);
      l_run = l_run*alpha + rs;
      m_run = m_new;
      #pragma unroll
      for(int t=0;t<4;++t) oacc[t] *= alpha;
      asm volatile("s_waitcnt lgkmcnt(0)" ::: "memory");   // wave-private PT2 ready
      // PV: O^T += Vt * P^T ; B-fragment = one b128 from PT2
      #pragma unroll
      for(int kh=0;kh<4;++kh){
        s16x8 pbig = *(const s16x8*)(prow + ((kh*64 + g*16) ^ swzP));
        #pragma unroll
        for(int t=0;t<4;++t){
          int vrow = t*16 + l15;
          const char* vr = (const char*)VtL + vrow*256 + ((kh*64 + g*16) ^ ((vrow&15)<<4));
          s16x8 va = *(const s16x8*)vr;
          oacc[t] = mfma_16x16x32_bf16(va, pbig, oacc[t]);
        }
      }
      __syncthreads();              // all waves done reading KL/VtL
      if(c < 3){ WRITEC(); __syncthreads(); }
    }

    // ---- epilogue: transpose numerator once (obuf = PT2 union), b128 both ways
    #pragma unroll
    for(int t=0;t<4;++t){
      fx4 w = oacc[t];
      *(fx4*)(prow + ((t*64 + g*16) ^ swzP)) = w;
    }
    asm volatile("s_waitcnt lgkmcnt(0)" ::: "memory");

    int r = lane>>2, cbo = (lane&3)*16;
    const char* orow = UA[wv] + r*256;
    int swzR = (r&15)<<4;
    fx4 N0 = *(const fx4*)(orow + (((lane&3)*64 +  0) ^ swzR));
    fx4 N1 = *(const fx4*)(orow + (((lane&3)*64 + 16) ^ swzR));
    fx4 N2 = *(const fx4*)(orow + (((lane&3)*64 + 32) ^ swzR));
    fx4 N3 = *(const fx4*)(orow + (((lane&3)*64 + 48) ^ swzR));
    float m_r = __shfl(m_run, r, 64);
    float l_r = __shfl(l_run, r, 64);
    float mke0 = mask_lds[512], mke1 = mask_lds[513];
    bool valid = (r < 8);

    #pragma unroll
    for(int p=0;p<8;++p){
      // entity scores via shuffle from the se-holding lane (pe=2p,2p+1; query=r)
      int srcl = (p>>1)*16 + r;
      float s0 = __shfl(se[(2*p)&3],   srcl, 64)*scale + mke0;
      float s1 = __shfl(se[(2*p+1)&3], srcl, 64)*scale + mke1;
      float mp = fmaxf(m_r, fmaxf(s0, s1));
      float al = __expf(m_r - mp);
      float p0 = __expf(s0-mp), p1 = __expf(s1-mp);
      float linv = 1.0f/(l_r*al + p0 + p1);
      const u16* vep = VeT + ((u64)(b*8+p)*16u + h)*128u + cbo*2;   // L2-resident
      u16 ve[32];
      {
        u32x4 w0 = *(const u32x4*)vep;
        u32x4 w1 = *(const u32x4*)(vep+8);
        u32x4 w2 = *(const u32x4*)(vep+16);
        u32x4 w3 = *(const u32x4*)(vep+24);
        __builtin_memcpy(ve,    &w0, 16);
        __builtin_memcpy(ve+8,  &w1, 16);
        __builtin_memcpy(ve+16, &w2, 16);
        __builtin_memcpy(ve+24, &w3, 16);
      }
      float o[16];
      #pragma unroll
      for(int j=0;j<4;++j){
        o[j]    = (N0[j]*al + p0*bf2f(ve[2*j])      + p1*bf2f(ve[2*j+1]))*linv;
        o[4+j]  = (N1[j]*al + p0*bf2f(ve[8+2*j])    + p1*bf2f(ve[8+2*j+1]))*linv;
        o[8+j]  = (N2[j]*al + p0*bf2f(ve[16+2*j])   + p1*bf2f(ve[16+2*j+1]))*linv;
        o[12+j] = (N3[j]*al + p0*bf2f(ve[24+2*j])   + p1*bf2f(ve[24+2*j+1]))*linv;
      }
      if(valid){
        float* og = outw + ((u64)(b*8+p)*512u + q0 + r)*1024u + h*64 + cbo;
        *(fx4*)og      = *(const fx4*)&o[0];
        *(fx4*)(og+4)  = *(const fx4*)&o[4];
        *(fx4*)(og+8)  = *(const fx4*)&o[8];
        *(fx4*)(og+12) = *(const fx4*)&o[12];
      }
    }
  } else {
    // =================== entity path (LDS carved from KL region) ===================
    int p = blockIdx.x - 16;
    u64 ebase = (u64)(b*8+p)*16u + h;
    float* s0_ = (float*)KL;                       // [516]
    float* s1_ = s0_ + 516;                        // [516]
    float* qwl = (float*)((char*)KL + 4160);       // [128]
    float* qel = qwl + 128;                        // [128]
    float* red_ = qel + 128;                       // [16]
    if(tid < 128){
      int r = tid>>6, d = tid&63;
      qwl[r*64+d] = bf2f(Qe2w[(ebase*2 + r)*64 + d]);
      qel[r*64+d] = bf2f(Qe2e[(ebase*2 + r)*64 + d]);
    }
    __syncthreads();
    const u16* Kpan = Kw + (u64)(b*16+h)*512u*64u;
    for(int k=tid;k<512;k+=256){
      const u16* kr = Kpan + (u64)k*64u;
      float d0=0.f, d1=0.f;
      #pragma unroll
      for(int j=0;j<64;j+=8){
        s16x8 kv = *(const s16x8*)(kr+j);
        #pragma unroll
        for(int x=0;x<8;++x){
          float kf = bf2f((u16)kv[x]);
          d0 += qwl[j+x]*kf;
          d1 += qwl[64+j+x]*kf;
        }
      }
      float mk = msk[b*514 + k];
      s0_[k] = d0*0.125f + mk;
      s1_[k] = d1*0.125f + mk;
    }
    if(tid < 4){
      int r = tid>>1, e = tid&1;
      const u16* kr = Ke + (ebase*2 + e)*64;
      float dd = 0.f;
      for(int j=0;j<64;++j) dd += qel[r*64+j]*bf2f(kr[j]);
      float* sl = (r==0)?s0_:s1_;
      sl[512+e] = dd*0.125f + msk[b*514 + 512 + e];
    }
    __syncthreads();
    float mx0=-3e38f, mx1=-3e38f;
    for(int k=tid;k<514;k+=256){ mx0=fmaxf(mx0,s0_[k]); mx1=fmaxf(mx1,s1_[k]); }
    #pragma unroll
    for(int off=32; off; off>>=1){
      mx0 = fmaxf(mx0, __shfl_xor(mx0, off, 64));
      mx1 = fmaxf(mx1, __shfl_xor(mx1, off, 64));
    }
    if(lane==0){ red_[wv]=mx0; red_[8+wv]=mx1; }
    __syncthreads();
    float m0 = fmaxf(fmaxf(red_[0],red_[1]),fmaxf(red_[2],red_[3]));
    float m1 = fmaxf(fmaxf(red_[8],red_[9]),fmaxf(red_[10],red_[11]));
    float sm0=0.f, sm1=0.f;
    for(int k=tid;k<514;k+=256){
      float e0 = __expf(s0_[k]-m0); s0_[k]=e0; sm0+=e0;
      float e1 = __expf(s1_[k]-m1); s1_[k]=e1; sm1+=e1;
    }
    #pragma unroll
    for(int off=32; off; off>>=1){
      sm0 += __shfl_xor(sm0, off, 64);
      sm1 += __shfl_xor(sm1, off, 64);
    }
    if(lane==0){ red_[4+wv]=sm0; red_[12+wv]=sm1; }
    __syncthreads();
    float l0 = red_[4]+red_[5]+red_[6]+red_[7];
    float l1 = red_[12]+red_[13]+red_[14]+red_[15];
    if(tid < 128){
      int r = tid>>6, d = tid&63;
      const float* sl = (r==0)?s0_:s1_;
      const u16* vr = VwT + ((u64)(b*16+h)*64u + d)*512u;
      float acc = 0.f;
      for(int k=0;k<512;k+=8){
        s16x8 vv = *(const s16x8*)(vr+k);
        #pragma unroll
        for(int x=0;x<8;++x) acc += sl[k+x]*bf2f((u16)vv[x]);
      }
      const u16* ve = VeT + (ebase*64 + d)*2;
      acc += sl[512]*bf2f(ve[0]) + sl[513]*bf2f(ve[1]);
      float val = acc / ((r==0)?l0:l1);
      oute[(((u64)(b*8+p)*2u + r)*1024u + h*64 + d)] = val;
    }
  }
}

extern "C" void kernel_launch(void* const* d_in, const int* in_sizes, int n_in,
                              void* d_out, int out_size, void* d_ws, size_t ws_size,
                              hipStream_t stream)
{
  const float* words = (const float*)d_in[0];
  const float* ents  = (const float*)d_in[1];
  const float* amask = (const float*)d_in[2];
  const float* q_w   = (const float*)d_in[3];
  const float* q_b   = (const float*)d_in[4];
  const float* k_w   = (const float*)d_in[5];
  const float* k_b   = (const float*)d_in[6];
  const float* v_w   = (const float*)d_in[7];
  const float* v_b   = (const float*)d_in[8];
  const float* w2e_w = (const float*)d_in[9];
  const float* w2e_b = (const float*)d_in[10];
  const float* e2w_w = (const float*)d_in[11];
  const float* e2w_b = (const float*)d_in[12];
  const float* e2e_w = (const float*)d_in[13];
  const float* e2e_b = (const float*)d_in[14];

  const size_t MW = 1048576;   // u16 elements per 1024x1024 matrix
  u16* ws16 = (u16*)d_ws;
  if(ws_size < (11*MW + 5*32768)*sizeof(u16)) return;
  u16* WTq   = ws16 + 0*MW;
  u16* WTk   = ws16 + 1*MW;
  u16* WTv   = ws16 + 2*MW;
  u16* WTw2e = ws16 + 3*MW;
  u16* WTe2w = ws16 + 4*MW;
  u16* WTe2e = ws16 + 5*MW;
  u16* Qw    = ws16 + 6*MW;
  u16* Q2e   = ws16 + 7*MW;
  u16* Kwp   = ws16 + 8*MW;
  u16* VwTp  = ws16 + 9*MW;
  u16* Xbf   = ws16 + 10*MW;
  u16* Qe2w  = ws16 + 11*MW;
  u16* Qe2e  = Qe2w + 32768;
  u16* Kep   = Qe2e + 32768;
  u16* VeTp  = Kep + 32768;
  u16* Ebf   = VeTp + 32768;

  dim3 tb(256);
  k_prep<<<dim3(2064), tb, 0, stream>>>(q_w, k_w, v_w, w2e_w, e2w_w, e2e_w, ws16,
                                        words, Xbf, ents, Ebf);
  k_proj<<<dim3(16,9,4), tb, 0, stream>>>(Xbf, Ebf,
      WTq, WTw2e, WTk, WTv, WTe2w, WTe2e,
      q_b, w2e_b, k_b, v_b, e2w_b, e2e_b,
      Qw, Q2e, Kwp, VwTp, Qe2w, Qe2e, Kep, VeTp);
  k_attn<<<dim3(24,16,2), tb, 0, stream>>>(Qw, Q2e, Kwp, VwTp, Kep, VeTp,
      Qe2w, Qe2e, amask, (float*)d_out, (float*)d_out + 8388608u);
}

// Round 13
// 60.577 us; speedup vs baseline: 1.1362x; 1.1362x over previous
//
#include <hip/hip_runtime.h>
#include <hip/hip_bf16.h>

typedef __attribute__((ext_vector_type(8))) short s16x8;
typedef __attribute__((ext_vector_type(4))) float fx4;
typedef __attribute__((ext_vector_type(4))) unsigned int u32x4;
typedef unsigned short u16;
typedef unsigned int   u32;
typedef unsigned long long u64;

#define DI __device__ __forceinline__

// B=2, W=512, E=2, P=8, H=1024, NH=16, D=64, T=514
// External I/O: float32. Internal workspace: bf16 (MFMA).

DI float bf2f(u16 x){ u32 u = ((u32)x)<<16; float f; __builtin_memcpy(&f,&u,4); return f; }
DI u16 f2bf(float f){ u32 u; __builtin_memcpy(&u,&f,4); u = (u + 0x7fffu + ((u>>16)&1u))>>16; return (u16)u; }

DI fx4 mfma_16x16x32_bf16(s16x8 a, s16x8 b, fx4 c){
  return __builtin_amdgcn_mfma_f32_16x16x32_bf16(a,b,c,0,0,0);
}

// ---------------- K_prep: fused weight transpose (f32 k,n -> bf16 n,k) + activations cvt ----
__global__ __launch_bounds__(256) void k_prep(
    const float* __restrict__ s0, const float* __restrict__ s1, const float* __restrict__ s2,
    const float* __restrict__ s3, const float* __restrict__ s4, const float* __restrict__ s5,
    u16* __restrict__ dstbase,
    const float* __restrict__ words, u16* __restrict__ Xbf,
    const float* __restrict__ ents,  u16* __restrict__ Ebf)
{
  __shared__ __align__(16) u16 tile[64][72];
  int bx = blockIdx.x, tid = threadIdx.x;
  if(bx < 1536){
    int z = bx>>8, t = bx&255;
    const float* src = (z==0)?s0:(z==1)?s1:(z==2)?s2:(z==3)?s3:(z==4)?s4:s5;
    u16* dst = dstbase + (u64)z*1048576u;
    int kt = (t&15)*64, nt = (t>>4)*64;
    #pragma unroll
    for(int it=0; it<2; ++it){
      int c = it*256 + tid;
      int r = c>>3, col = (c&7)*8;
      const float* sp = src + (u64)(kt+r)*1024u + nt + col;
      fx4 a = *(const fx4*)sp;
      fx4 b = *(const fx4*)(sp+4);
      u16 o[8];
      o[0]=f2bf(a[0]); o[1]=f2bf(a[1]); o[2]=f2bf(a[2]); o[3]=f2bf(a[3]);
      o[4]=f2bf(b[0]); o[5]=f2bf(b[1]); o[6]=f2bf(b[2]); o[7]=f2bf(b[3]);
      __builtin_memcpy(&tile[r][col], o, 16);
    }
    __syncthreads();
    #pragma unroll
    for(int it=0; it<2; ++it){
      int c = it*256 + tid;
      int nr = c>>3, kc = (c&7)*8;
      u16 tmp[8];
      #pragma unroll
      for(int j=0;j<8;++j) tmp[j] = tile[kc+j][nr];
      u32x4 v; __builtin_memcpy(&v, tmp, 16);
      *(u32x4*)(dst + (u64)(nt+nr)*1024u + kt + kc) = v;
    }
  } else {
    const float* src; u16* dst; int i;
    if(bx < 2048){ src = words; dst = Xbf; i = ((bx-1536)*256 + tid)*8; }
    else         { src = ents;  dst = Ebf; i = ((bx-2048)*256 + tid)*8; }
    fx4 a = *(const fx4*)(src+i);
    fx4 b = *(const fx4*)(src+i+4);
    u16 o[8];
    o[0]=f2bf(a[0]); o[1]=f2bf(a[1]); o[2]=f2bf(a[2]); o[3]=f2bf(a[3]);
    o[4]=f2bf(b[0]); o[5]=f2bf(b[1]); o[6]=f2bf(b[2]); o[7]=f2bf(b[3]);
    u32x4 v; __builtin_memcpy(&v,o,16);
    *(u32x4*)(dst+i)=v;
  }
}

// ---------------- K_proj: all 8 projections in one launch (round-5 structure) --------------
__global__ __launch_bounds__(256) void k_proj(
    const u16* __restrict__ Xbf, const u16* __restrict__ Ebf,
    const u16* __restrict__ wtq, const u16* __restrict__ wtw2e,
    const u16* __restrict__ wtk, const u16* __restrict__ wtv,
    const u16* __restrict__ wte2w, const u16* __restrict__ wte2e,
    const float* __restrict__ qb, const float* __restrict__ w2eb,
    const float* __restrict__ kb, const float* __restrict__ vb,
    const float* __restrict__ e2wb, const float* __restrict__ e2eb,
    u16* __restrict__ Qw, u16* __restrict__ Q2e, u16* __restrict__ Kwp, u16* __restrict__ VwTp,
    u16* __restrict__ Qe2w, u16* __restrict__ Qe2e, u16* __restrict__ Kep, u16* __restrict__ VeTp)
{
  __shared__ __align__(16) u16 XL[128*64];
  __shared__ __align__(16) u16 WL[128*64];
  int tid = threadIdx.x;
  int z = blockIdx.z;
  int wv = tid>>6, lane = tid&63, l15 = lane&15, g = lane>>4;

  if(blockIdx.y < 8){
    const u16* WT  = (z==0)?wtq:(z==1)?wtw2e:(z==2)?wtk:wtv;
    const float* bias = (z==0)?qb :(z==1)?w2eb :(z==2)?kb :vb;
    u16* out       = (z==0)?Qw :(z==1)?Q2e :(z==2)?Kwp :VwTp;
    int nt = blockIdx.x*64;
    int mt = blockIdx.y*128;
    int wr = (wv>>1)*64, wc = (wv&1)*32;
    fx4 acc[4][2] = {};
    u32x4 rx[4], rw[2];
    #pragma unroll
    for(int it=0; it<4; ++it){
      int c = it*256 + tid;
      int r = c>>3, cb = (c&7)*16, scb = cb ^ ((r&7)<<4);
      rx[it] = *(const u32x4*)((const char*)Xbf + ((u64)(mt+r)*1024u)*2u + scb);
    }
    #pragma unroll
    for(int it=0; it<2; ++it){
      int c = it*256 + tid;
      int r = c>>3, cb = (c&7)*16, scb = cb ^ ((r&7)<<4);
      rw[it] = *(const u32x4*)((const char*)WT + ((u64)(nt+r)*1024u)*2u + scb);
    }
    #pragma unroll
    for(int it=0; it<4; ++it) *(u32x4*)((char*)XL + (it*256+tid)*16) = rx[it];
    #pragma unroll
    for(int it=0; it<2; ++it) *(u32x4*)((char*)WL + (it*256+tid)*16) = rw[it];
    __syncthreads();
    for(int t=0; t<16; ++t){
      int kn = (t+1)*64;
      if(t < 15){
        #pragma unroll
        for(int it=0; it<4; ++it){
          int c = it*256 + tid;
          int r = c>>3, cb = (c&7)*16, scb = cb ^ ((r&7)<<4);
          rx[it] = *(const u32x4*)((const char*)Xbf + ((u64)(mt+r)*1024u + kn)*2u + scb);
        }
        #pragma unroll
        for(int it=0; it<2; ++it){
          int c = it*256 + tid;
          int r = c>>3, cb = (c&7)*16, scb = cb ^ ((r&7)<<4);
          rw[it] = *(const u32x4*)((const char*)WT + ((u64)(nt+r)*1024u + kn)*2u + scb);
        }
      }
      #pragma unroll
      for(int ks=0; ks<2; ++ks){
        s16x8 af[4], bfv[2];
        #pragma unroll
        for(int i=0;i<4;++i){
          int ra = wr + i*16 + l15;
          af[i]  = *(const s16x8*)((const char*)XL + ra*128 + ((ks*64 + g*16) ^ ((ra&7)<<4)));
        }
        #pragma unroll
        for(int j=0;j<2;++j){
          int rb = wc + j*16 + l15;
          bfv[j] = *(const s16x8*)((const char*)WL + rb*128 + ((ks*64 + g*16) ^ ((rb&7)<<4)));
        }
        #pragma unroll
        for(int i=0;i<4;++i)
          #pragma unroll
          for(int j=0;j<2;++j)
            acc[i][j] = mfma_16x16x32_bf16(af[i], bfv[j], acc[i][j]);
      }
      __syncthreads();
      if(t < 15){
        #pragma unroll
        for(int it=0; it<4; ++it) *(u32x4*)((char*)XL + (it*256+tid)*16) = rx[it];
        #pragma unroll
        for(int it=0; it<2; ++it) *(u32x4*)((char*)WL + (it*256+tid)*16) = rw[it];
        __syncthreads();
      }
    }
    bool vmode = (z==3);
    #pragma unroll
    for(int j=0;j<2;++j){
      int n = nt + wc + j*16 + l15;
      float bv = bias[n];
      int h = n>>6, d = n&63;
      #pragma unroll
      for(int i=0;i<4;++i){
        #pragma unroll
        for(int q=0;q<4;++q){
          int m = mt + wr + i*16 + g*4 + q;
          int bb = m>>9, wrow = m&511;
          float v = acc[i][j][q] + bv;
          u64 o = vmode ? (((u64)(bb*16+h)*64u + d)*512u + wrow)
                        : (((u64)(bb*16+h)*512u + wrow)*64u + d);
          out[o] = f2bf(v);
        }
      }
    }
  } else {
    if(blockIdx.x >= 8) return;
    const u16* WT  = (z==0)?wte2w:(z==1)?wte2e:(z==2)?wtk:wtv;
    const float* bias = (z==0)?e2wb :(z==1)?e2eb :(z==2)?kb :vb;
    u16* out       = (z==0)?Qe2w :(z==1)?Qe2e :(z==2)?Kep :VeTp;
    int nt = blockIdx.x*128;
    int wc = wv*32;
    fx4 acc[2][2] = {};
    for(int kk=0; kk<1024; kk+=64){
      {
        int r = tid>>3, cb = (tid&7)*16, scb = cb ^ ((r&7)<<4);
        *(u32x4*)((char*)XL + r*128 + cb) =
          *(const u32x4*)((const char*)Ebf + ((u64)r*1024u + kk)*2u + scb);
      }
      #pragma unroll
      for(int it=0; it<4; ++it){
        int c = it*256 + tid;
        int r = c>>3, cb = (c&7)*16, scb = cb ^ ((r&7)<<4);
        *(u32x4*)((char*)WL + r*128 + cb) =
          *(const u32x4*)((const char*)WT + ((u64)(nt+r)*1024u + kk)*2u + scb);
      }
      __syncthreads();
      #pragma unroll
      for(int ks=0; ks<2; ++ks){
        s16x8 af[2], bfv[2];
        #pragma unroll
        for(int i=0;i<2;++i){
          int ra = i*16 + l15;
          af[i]  = *(const s16x8*)((const char*)XL + ra*128 + ((ks*64 + g*16) ^ ((ra&7)<<4)));
          int rb = wc + i*16 + l15;
          bfv[i] = *(const s16x8*)((const char*)WL + rb*128 + ((ks*64 + g*16) ^ ((rb&7)<<4)));
        }
        #pragma unroll
        for(int i=0;i<2;++i)
          #pragma unroll
          for(int j=0;j<2;++j)
            acc[i][j] = mfma_16x16x32_bf16(af[i], bfv[j], acc[i][j]);
      }
      __syncthreads();
    }
    bool vmode = (z==3);
    #pragma unroll
    for(int j=0;j<2;++j){
      int n = nt + wc + j*16 + l15;
      float bv = bias[n];
      int h = n>>6, d = n&63;
      #pragma unroll
      for(int i=0;i<2;++i){
        #pragma unroll
        for(int q=0;q<4;++q){
          int m = i*16 + g*4 + q;     // 0..31 = ((b*8+p)*2+e)
          int bb = m>>4, p = (m>>1)&7, e = m&1;
          float v = acc[i][j][q] + bv;
          u64 base = ((u64)(bb*8+p)*16u + h);
          u64 o = vmode ? ((base*64u + d)*2u + e)
                        : ((base*2u + e)*64u + d);
          out[o] = f2bf(v);
        }
      }
    }
  }
}

// ---------------- K_attn: word-query flash attention + entity-query rows ----------------
// 1-D grid of 512 with XCD-grouping swizzle: all 16 blocks sharing one (b,h) KV panel land
// on ONE XCD (position = (g%8) + 8*((g/8)*16 + k), bijective) -> 15/16 blocks hit warm L2.
// Decoded x<8 -> word path (qc=x); x>=8 -> entity path (p=x-8). Round-9 structure:
// KVBLK=128 (4 chunks), K+V staged in LDS with reg-prefetch, entity scores via 2 MFMAs,
// Ve pre-staged, PT/obuf LDS union.
__global__ __launch_bounds__(256) void k_attn(
    const u16* __restrict__ Qw,  const u16* __restrict__ Q2e,
    const u16* __restrict__ Kw,  const u16* __restrict__ VwT,
    const u16* __restrict__ Ke,  const u16* __restrict__ VeT,
    const u16* __restrict__ Qe2w, const u16* __restrict__ Qe2e,
    const float* __restrict__ msk, float* __restrict__ outw, float* __restrict__ oute)
{
  const float scale = 0.125f;
  __shared__ __align__(16) u16 KL[128*64];        // 16 KB, rows 128B, swz ((r&7)<<4)
  __shared__ __align__(16) u16 VtL[64*128];       // 16 KB, rows 256B, swz ((r&15)<<4)
  __shared__ __align__(16) char UA[4][4608];      // union: PT u16[128][18] | obuf f32[16][68]
  __shared__ __align__(16) float mask_lds[576];
  __shared__ __align__(16) float se_lds[4][16][20];
  __shared__ __align__(16) u16 velds[8*128];      // [p][d][e]
  __shared__ float s_lds[2][516];
  __shared__ float qwl[2][64];
  __shared__ float qel[2][64];
  __shared__ float red[2][8];
  int tid = threadIdx.x;
  // XCD-grouping decode: bid -> (b, h, x)
  int bid = blockIdx.x;
  int xcd = bid & 7, slot = bid >> 3;
  int gq = slot >> 4, k_ = slot & 15;
  int g_ = gq*8 + xcd;            // 0..31 = b*16+h
  int b = g_ >> 4, h = g_ & 15;
  int xpart = k_;                 // 0..15
  int wv = tid>>6, lane = tid&63, l15 = lane&15, g = lane>>4;

  if(xpart < 8){
    // =================== word path ===================
    int qc = xpart;
    int q0 = qc*64 + wv*16;

    for(int i=tid;i<576;i+=256) mask_lds[i] = (i<514) ? msk[b*514+i] : 0.f;
    if(tid < 128){
      int p = tid>>4, o = (tid&15)*8;
      *(u32x4*)&velds[p*128 + o] = *(const u32x4*)(VeT + ((u64)(b*8+p)*16u + h)*128u + o);
    }

    // Q and Q2 B-fragments (lane: col=query l15, elems 8g+j)
    const u16* Qrow = Qw + ((u64)(b*16+h)*512u + q0 + l15)*64u;
    s16x8 qf0 = *(const s16x8*)(Qrow + g*8);
    s16x8 qf1 = *(const s16x8*)(Qrow + 32 + g*8);
    const u16* Q2row = Q2e + ((u64)(b*16+h)*512u + q0 + l15)*64u;
    s16x8 q2f0 = *(const s16x8*)(Q2row + g*8);
    s16x8 q2f1 = *(const s16x8*)(Q2row + 32 + g*8);
    // Ke A-fragment: lane row = pe = l15 (p=l15>>1, e=l15&1)
    const u16* kerow = Ke + ((u64)(b*8+(l15>>1))*16u + h)*128u + (u64)(l15&1)*64u;
    s16x8 keA0 = *(const s16x8*)(kerow + g*8);
    s16x8 keA1 = *(const s16x8*)(kerow + 32 + g*8);
    // entity scores: D[pe=g*4+qq][query=l15]
    {
      fx4 se = {0.f,0.f,0.f,0.f};
      se = mfma_16x16x32_bf16(keA0, q2f0, se);
      se = mfma_16x16x32_bf16(keA1, q2f1, se);
      *(fx4*)&se_lds[wv][l15][g*4] = se;
    }

    const char* Kpan = (const char*)(Kw  + (u64)(b*16+h)*512u*64u);   // 512 rows x 128B
    const char* Vpan = (const char*)(VwT + (u64)(b*16+h)*64u*512u);   // 64 rows x 1024B

    u32x4 rk[4], rv[4];
    auto LOADC = [&](int c){
      #pragma unroll
      for(int it=0;it<4;++it){
        int idx = it*256+tid;
        int r = idx>>3, cb = (idx&7)*16;
        rk[it] = *(const u32x4*)(Kpan + (u64)(c*128+r)*128u + cb);
        int vrr = idx>>4, vcb = (idx&15)*16;
        rv[it] = *(const u32x4*)(Vpan + (u64)vrr*1024u + (u64)c*256u + vcb);
      }
    };
    auto WRITEC = [&](){
      #pragma unroll
      for(int it=0;it<4;++it){
        int idx = it*256+tid;
        int r = idx>>3, cb = (idx&7)*16;
        *(u32x4*)((char*)KL + r*128 + (cb ^ ((r&7)<<4))) = rk[it];
        int vrr = idx>>4, vcb = (idx&15)*16;
        *(u32x4*)((char*)VtL + vrr*256 + (vcb ^ ((vrr&15)<<4))) = rv[it];
      }
    };

    LOADC(0); WRITEC();
    float m_run = -3.0e38f, l_run = 0.f;
    fx4 oacc[4] = {};
    __syncthreads();       // chunk 0 + mask + velds ready

    u16 (*PT)[18] = (u16(*)[18])UA[wv];
    for(int c=0;c<4;++c){
      if(c < 3) LOADC(c+1);         // next chunk in flight during compute
      // QK: S^T = K * Q^T, 128 keys
      float sv[8][4];
      #pragma unroll
      for(int s=0;s<8;++s){
        int row = s*16 + l15;
        const char* kr = (const char*)KL + row*128;
        int sz = (row&7)<<4;
        s16x8 ka0 = *(const s16x8*)(kr + ((g*16) ^ sz));
        s16x8 ka1 = *(const s16x8*)(kr + ((64 + g*16) ^ sz));
        fx4 st = {0.f,0.f,0.f,0.f};
        st = mfma_16x16x32_bf16(ka0, qf0, st);
        st = mfma_16x16x32_bf16(ka1, qf1, st);
        fx4 mk = *(const fx4*)&mask_lds[c*128 + s*16 + g*4];
        #pragma unroll
        for(int q=0;q<4;++q) sv[s][q] = st[q]*scale + mk[q];
      }
      float cm = -3.0e38f;
      #pragma unroll
      for(int s=0;s<8;++s)
        #pragma unroll
        for(int q=0;q<4;++q) cm = fmaxf(cm, sv[s][q]);
      cm = fmaxf(cm, __shfl_xor(cm, 16, 64));
      cm = fmaxf(cm, __shfl_xor(cm, 32, 64));
      float m_new = fmaxf(m_run, cm);
      float alpha = __expf(m_run - m_new);
      float rs = 0.f;
      #pragma unroll
      for(int s=0;s<8;++s){
        #pragma unroll
        for(int q=0;q<4;++q){
          float e = __expf(sv[s][q] - m_new);
          rs += e;
          PT[s*16 + g*4 + q][l15] = f2bf(e);
        }
      }
      rs += __shfl_xor(rs, 16, 64);
      rs += __shfl_xor(rs, 32, 64);
      l_run = l_run*alpha + rs;
      m_run = m_new;
      #pragma unroll
      for(int t=0;t<4;++t) oacc[t] *= alpha;
      asm volatile("s_waitcnt lgkmcnt(0)" ::: "memory");   // wave-private PT ready
      // PV: O^T += Vt * P^T
      #pragma unroll
      for(int kh=0;kh<4;++kh){
        u16 ptmp[8];
        #pragma unroll
        for(int j=0;j<8;++j) ptmp[j] = PT[kh*32 + g*8 + j][l15];
        s16x8 pbig; __builtin_memcpy(&pbig, ptmp, 16);
        #pragma unroll
        for(int t=0;t<4;++t){
          int vrow = t*16 + l15;
          const char* vr = (const char*)VtL + vrow*256 + ((kh*64 + g*16) ^ ((vrow&15)<<4));
          s16x8 va = *(const s16x8*)vr;
          oacc[t] = mfma_16x16x32_bf16(va, pbig, oacc[t]);
        }
      }
      __syncthreads();              // all waves done reading KL/VtL
      if(c < 3){ WRITEC(); __syncthreads(); }
    }

    // ---- epilogue: transpose numerator once (obuf = PT union), 8 p-corrections, no shuffles
    float (*obuf)[68] = (float(*)[68])UA[wv];
    #pragma unroll
    for(int t=0;t<4;++t)
      #pragma unroll
      for(int q=0;q<4;++q)
        obuf[l15][t*16 + g*4 + q] = oacc[t][q];
    asm volatile("s_waitcnt lgkmcnt(0)" ::: "memory");

    int r = lane>>2, cbo = (lane&3)*16;
    fx4 N0 = *(const fx4*)&obuf[r][cbo];
    fx4 N1 = *(const fx4*)&obuf[r][cbo+4];
    fx4 N2 = *(const fx4*)&obuf[r][cbo+8];
    fx4 N3 = *(const fx4*)&obuf[r][cbo+12];
    float m_r = __shfl(m_run, r, 64);
    float l_r = __shfl(l_run, r, 64);
    float mke0 = mask_lds[512], mke1 = mask_lds[513];

    for(int p=0;p<8;++p){
      float s0 = se_lds[wv][r][2*p]  *scale + mke0;
      float s1 = se_lds[wv][r][2*p+1]*scale + mke1;
      float mp = fmaxf(m_r, fmaxf(s0, s1));
      float al = __expf(m_r - mp);
      float p0 = __expf(s0-mp), p1 = __expf(s1-mp);
      float linv = 1.0f/(l_r*al + p0 + p1);
      const u16* vep = velds + p*128 + cbo*2;    // LDS, broadcast per 4-lane group
      u16 ve[32];
      {
        u32x4 w0 = *(const u32x4*)vep;
        u32x4 w1 = *(const u32x4*)(vep+8);
        u32x4 w2 = *(const u32x4*)(vep+16);
        u32x4 w3 = *(const u32x4*)(vep+24);
        __builtin_memcpy(ve,    &w0, 16);
        __builtin_memcpy(ve+8,  &w1, 16);
        __builtin_memcpy(ve+16, &w2, 16);
        __builtin_memcpy(ve+24, &w3, 16);
      }
      float o[16];
      #pragma unroll
      for(int j=0;j<4;++j){
        o[j]    = (N0[j]*al + p0*bf2f(ve[2*j])      + p1*bf2f(ve[2*j+1]))*linv;
        o[4+j]  = (N1[j]*al + p0*bf2f(ve[8+2*j])    + p1*bf2f(ve[8+2*j+1]))*linv;
        o[8+j]  = (N2[j]*al + p0*bf2f(ve[16+2*j])   + p1*bf2f(ve[16+2*j+1]))*linv;
        o[12+j] = (N3[j]*al + p0*bf2f(ve[24+2*j])   + p1*bf2f(ve[24+2*j+1]))*linv;
      }
      float* og = outw + ((u64)(b*8+p)*512u + q0 + r)*1024u + h*64 + cbo;
      *(fx4*)og      = *(const fx4*)&o[0];
      *(fx4*)(og+4)  = *(const fx4*)&o[4];
      *(fx4*)(og+8)  = *(const fx4*)&o[8];
      *(fx4*)(og+12) = *(const fx4*)&o[12];
    }
  } else {
    // =================== entity path ===================
    int p = xpart - 8;
    u64 ebase = (u64)(b*8+p)*16u + h;
    if(tid < 128){
      int r = tid>>6, d = tid&63;
      qwl[r][d] = bf2f(Qe2w[(ebase*2 + r)*64 + d]);
      qel[r][d] = bf2f(Qe2e[(ebase*2 + r)*64 + d]);
    }
    __syncthreads();
    const u16* Kpan = Kw + (u64)(b*16+h)*512u*64u;
    for(int k=tid;k<512;k+=256){
      const u16* kr = Kpan + (u64)k*64u;
      float d0=0.f, d1=0.f;
      #pragma unroll
      for(int j=0;j<64;j+=8){
        s16x8 kv = *(const s16x8*)(kr+j);
        #pragma unroll
        for(int x=0;x<8;++x){
          float kf = bf2f((u16)kv[x]);
          d0 += qwl[0][j+x]*kf;
          d1 += qwl[1][j+x]*kf;
        }
      }
      float mk = msk[b*514 + k];
      s_lds[0][k] = d0*0.125f + mk;
      s_lds[1][k] = d1*0.125f + mk;
    }
    if(tid < 4){
      int r = tid>>1, e = tid&1;
      const u16* kr = Ke + (ebase*2 + e)*64;
      float dd = 0.f;
      for(int j=0;j<64;++j) dd += qel[r][j]*bf2f(kr[j]);
      s_lds[r][512+e] = dd*0.125f + msk[b*514 + 512 + e];
    }
    __syncthreads();
    float mx0=-3e38f, mx1=-3e38f;
    for(int k=tid;k<514;k+=256){ mx0=fmaxf(mx0,s_lds[0][k]); mx1=fmaxf(mx1,s_lds[1][k]); }
    #pragma unroll
    for(int off=32; off; off>>=1){
      mx0 = fmaxf(mx0, __shfl_xor(mx0, off, 64));
      mx1 = fmaxf(mx1, __shfl_xor(mx1, off, 64));
    }
    if(lane==0){ red[0][wv]=mx0; red[1][wv]=mx1; }
    __syncthreads();
    float m0 = fmaxf(fmaxf(red[0][0],red[0][1]),fmaxf(red[0][2],red[0][3]));
    float m1 = fmaxf(fmaxf(red[1][0],red[1][1]),fmaxf(red[1][2],red[1][3]));
    float sm0=0.f, sm1=0.f;
    for(int k=tid;k<514;k+=256){
      float e0 = __expf(s_lds[0][k]-m0); s_lds[0][k]=e0; sm0+=e0;
      float e1 = __expf(s_lds[1][k]-m1); s_lds[1][k]=e1; sm1+=e1;
    }
    #pragma unroll
    for(int off=32; off; off>>=1){
      sm0 += __shfl_xor(sm0, off, 64);
      sm1 += __shfl_xor(sm1, off, 64);
    }
    if(lane==0){ red[0][4+wv]=sm0; red[1][4+wv]=sm1; }
    __syncthreads();
    float l0 = red[0][4]+red[0][5]+red[0][6]+red[0][7];
    float l1 = red[1][4]+red[1][5]+red[1][6]+red[1][7];
    if(tid < 128){
      int r = tid>>6, d = tid&63;
      const u16* vr = VwT + ((u64)(b*16+h)*64u + d)*512u;
      float acc = 0.f;
      for(int k=0;k<512;k+=8){
        s16x8 vv = *(const s16x8*)(vr+k);
        #pragma unroll
        for(int x=0;x<8;++x) acc += s_lds[r][k+x]*bf2f((u16)vv[x]);
      }
      const u16* ve = VeT + (ebase*64 + d)*2;
      acc += s_lds[r][512]*bf2f(ve[0]) + s_lds[r][513]*bf2f(ve[1]);
      float val = acc / ((r==0)?l0:l1);
      oute[(((u64)(b*8+p)*2u + r)*1024u + h*64 + d)] = val;
    }
  }
}

extern "C" void kernel_launch(void* const* d_in, const int* in_sizes, int n_in,
                              void* d_out, int out_size, void* d_ws, size_t ws_size,
                              hipStream_t stream)
{
  const float* words = (const float*)d_in[0];
  const float* ents  = (const float*)d_in[1];
  const float* amask = (const float*)d_in[2];
  const float* q_w   = (const float*)d_in[3];
  const float* q_b   = (const float*)d_in[4];
  const float* k_w   = (const float*)d_in[5];
  const float* k_b   = (const float*)d_in[6];
  const float* v_w   = (const float*)d_in[7];
  const float* v_b   = (const float*)d_in[8];
  const float* w2e_w = (const float*)d_in[9];
  const float* w2e_b = (const float*)d_in[10];
  const float* e2w_w = (const float*)d_in[11];
  const float* e2w_b = (const float*)d_in[12];
  const float* e2e_w = (const float*)d_in[13];
  const float* e2e_b = (const float*)d_in[14];

  const size_t MW = 1048576;   // u16 elements per 1024x1024 matrix
  u16* ws16 = (u16*)d_ws;
  if(ws_size < (11*MW + 5*32768)*sizeof(u16)) return;
  u16* WTq   = ws16 + 0*MW;
  u16* WTk   = ws16 + 1*MW;
  u16* WTv   = ws16 + 2*MW;
  u16* WTw2e = ws16 + 3*MW;
  u16* WTe2w = ws16 + 4*MW;
  u16* WTe2e = ws16 + 5*MW;
  u16* Qw    = ws16 + 6*MW;
  u16* Q2e   = ws16 + 7*MW;
  u16* Kwp   = ws16 + 8*MW;
  u16* VwTp  = ws16 + 9*MW;
  u16* Xbf   = ws16 + 10*MW;
  u16* Qe2w  = ws16 + 11*MW;
  u16* Qe2e  = Qe2w + 32768;
  u16* Kep   = Qe2e + 32768;
  u16* VeTp  = Kep + 32768;
  u16* Ebf   = VeTp + 32768;

  dim3 tb(256);
  k_prep<<<dim3(2064), tb, 0, stream>>>(q_w, k_w, v_w, w2e_w, e2w_w, e2e_w, ws16,
                                        words, Xbf, ents, Ebf);
  k_proj<<<dim3(16,9,4), tb, 0, stream>>>(Xbf, Ebf,
      WTq, WTw2e, WTk, WTv, WTe2w, WTe2e,
      q_b, w2e_b, k_b, v_b, e2w_b, e2e_b,
      Qw, Q2e, Kwp, VwTp, Qe2w, Qe2e, Kep, VeTp);
  k_attn<<<dim3(512), tb, 0, stream>>>(Qw, Q2e, Kwp, VwTp, Kep, VeTp,
      Qe2w, Qe2e, amask, (float*)d_out, (float*)d_out + 8388608u);
}